// Round 21
// baseline (237.821 us; speedup 1.0000x reference)
//
#include <hip/hip_runtime.h>

// Problem constants (match reference)
#define D 128
#define H 8
#define DK 16
#define FFDIM 512
#define NTYPES 5
#define LN_EPS 1e-5f

typedef __bf16 bf16x8 __attribute__((ext_vector_type(8)));
typedef float f32x4 __attribute__((ext_vector_type(4)));
typedef unsigned short ushort_t;
typedef unsigned int uint_t;

__device__ inline ushort_t bfbits(float f) {
  __bf16 b = (__bf16)f;
  return __builtin_bit_cast(ushort_t, b);
}

// ---------------------------------------------------------------------------
// K0: detect mask dtype (byte-bool vs int32). flag=1 for byte masks.
// ---------------------------------------------------------------------------
__global__ void detect_kernel(const unsigned char* __restrict__ m8, int E,
                              int* __restrict__ flag) {
  int lane = threadIdx.x;  // 64 threads, 1 wave
  int s = 1;
  if (lane < E) {
    s = 0;
#pragma unroll
    for (int i = 0; i < NTYPES; ++i) s += (m8[(size_t)i * E + lane] != 0);
  }
  unsigned long long b = __ballot(s == 1);
  if (lane == 0) *flag = (b == ~0ull) ? 1 : 0;
}

__device__ inline int decode_etype(const unsigned char* __restrict__ m8,
                                   int E, int e, int is8) {
  int t = 0;
  if (is8) {
#pragma unroll
    for (int i = 1; i < NTYPES; ++i) t += i * (m8[(size_t)i * E + e] != 0);
  } else {
    const int* m32 = (const int*)m8;
#pragma unroll
    for (int i = 1; i < NTYPES; ++i) t += i * (m32[(size_t)i * E + e] != 0);
  }
  return t > (NTYPES - 1) ? (NTYPES - 1) : t;
}

// ---------------------------------------------------------------------------
// K1b: convert a row-major f32 weight [K][N] into MFMA B-fragment order, bf16 hi.
// ---------------------------------------------------------------------------
__global__ void conv_frag_kernel(const float* __restrict__ W,
                                 ushort_t* __restrict__ hi,
                                 int K, int Ncol, size_t matW, size_t matF) {
  int gid = blockIdx.x * 256 + threadIdx.x;
  int total = (Ncol / 16) * (K / 32) * 64;
  if (gid >= total) return;
  const float* Wm = W + (size_t)blockIdx.y * matW;
  ushort_t* him = hi + (size_t)blockIdx.y * matF;
  int l = gid & 63;
  int ck = gid >> 6;
  int kk = ck % (K / 32);
  int c = ck / (K / 32);
  int row0 = kk * 32 + (l >> 4) * 8;
  int col = c * 16 + (l & 15);
  size_t ob = (size_t)gid * 8;
#pragma unroll
  for (int j = 0; j < 8; ++j) {
    float w = Wm[(size_t)(row0 + j) * Ncol + col];
    __bf16 h = (__bf16)w;
    him[ob + j] = __builtin_bit_cast(ushort_t, h);
  }
}

// ---------------------------------------------------------------------------
// K2: fused LN1 + proj via MFMA. 64 rows/block, 4 waves. z hi/lo split.
// ---------------------------------------------------------------------------
__global__ __launch_bounds__(256, 4) void projln_kernel(
    const float* __restrict__ x, const float* __restrict__ g,
    const float* __restrict__ b, const ushort_t* __restrict__ wkh,
    const float* __restrict__ bk, ushort_t* __restrict__ P, int n) {
  __shared__ ushort_t zsh[64 * D];
  __shared__ ushort_t zsl[64 * D];
  int tid = threadIdx.x, w = tid >> 6, l = tid & 63;
  int n0 = blockIdx.x * 64;

  for (int i = w; i < 64; i += 4) {
    int r = n0 + i;
    float v0 = 0.f, v1 = 0.f;
    if (r < n) {
      v0 = x[(size_t)r * D + l];
      v1 = x[(size_t)r * D + 64 + l];
    }
    float s = v0 + v1, ss = v0 * v0 + v1 * v1;
    for (int o = 32; o; o >>= 1) { s += __shfl_xor(s, o); ss += __shfl_xor(ss, o); }
    float mu = s * (1.f / D);
    float var = ss * (1.f / D) - mu * mu;
    float rs = rsqrtf(var + LN_EPS);
    float z0 = (v0 - mu) * rs * g[l] + b[l];
    float z1 = (v1 - mu) * rs * g[l + 64] + b[l + 64];
    int sw = (i & 7) << 3;
    int e0 = (i * D + l) ^ sw;
    int e1 = (i * D + l + 64) ^ sw;
    __bf16 h0 = (__bf16)z0, h1 = (__bf16)z1;
    zsh[e0] = __builtin_bit_cast(ushort_t, h0);
    zsh[e1] = __builtin_bit_cast(ushort_t, h1);
    __bf16 l0 = (__bf16)(z0 - (float)h0), l1 = (__bf16)(z1 - (float)h1);
    zsl[e0] = __builtin_bit_cast(ushort_t, l0);
    zsl[e1] = __builtin_bit_cast(ushort_t, l1);
  }
  __syncthreads();

  int lrow = w * 16 + (l & 15);
  int koff = (l >> 4) * 8;
  bf16x8 ah[4], al[4];
#pragma unroll
  for (int kk = 0; kk < 4; ++kk) {
    int e = (lrow * D + kk * 32 + koff) ^ ((lrow & 7) << 3);
    ah[kk] = *(const bf16x8*)(zsh + e);
    al[kk] = *(const bf16x8*)(zsl + e);
  }

  int col16 = l & 15, rgrp = (l >> 4) * 4;
  int rowbase = n0 + w * 16;
  for (int t = 0; t < NTYPES; ++t) {
    const ushort_t* bh0 = wkh + (size_t)t * (D * D);
    ushort_t* Pt = P + (size_t)t * n * D;
#pragma unroll
    for (int cp = 0; cp < 4; ++cp) {
      bf16x8 Bh[2][4];
#pragma unroll
      for (int cc = 0; cc < 2; ++cc)
#pragma unroll
        for (int kk = 0; kk < 4; ++kk) {
          size_t o = ((size_t)((cp * 2 + cc) * 4 + kk) * 64 + l) * 8;
          Bh[cc][kk] = *(const bf16x8*)(bh0 + o);
        }
      f32x4 aa[2], ac[2];
#pragma unroll
      for (int cc = 0; cc < 2; ++cc) {
        float bias = bk[t * D + (cp * 2 + cc) * 16 + col16];
        aa[cc] = (f32x4){bias, bias, bias, bias};
        ac[cc] = (f32x4){0.f, 0.f, 0.f, 0.f};
      }
#pragma unroll
      for (int kk = 0; kk < 4; ++kk)
#pragma unroll
        for (int cc = 0; cc < 2; ++cc) {
          aa[cc] = __builtin_amdgcn_mfma_f32_16x16x32_bf16(ah[kk], Bh[cc][kk], aa[cc], 0, 0, 0);
          ac[cc] = __builtin_amdgcn_mfma_f32_16x16x32_bf16(al[kk], Bh[cc][kk], ac[cc], 0, 0, 0);
        }
#pragma unroll
      for (int cc = 0; cc < 2; ++cc)
#pragma unroll
        for (int r = 0; r < 4; ++r) {
          int row = rowbase + rgrp + r;
          if (row < n)
            Pt[(size_t)row * D + (cp * 2 + cc) * 16 + col16] =
                bfbits(aa[cc][r] + ac[cc][r]);
        }
    }
  }
}

// ---------------------------------------------------------------------------
// K3: typed-CSR build by (src, etype)
// ---------------------------------------------------------------------------
__global__ void zero_kernel(int* __restrict__ p, int n) {
  int i = blockIdx.x * 256 + threadIdx.x;
  if (i < n) p[i] = 0;
}

// range-blocked + XCD-pinned histogram with inline etype decode
__global__ __launch_bounds__(256) void hist5_kernel(
    const int* __restrict__ edges, const unsigned char* __restrict__ masks,
    const int* __restrict__ flag, unsigned char* __restrict__ etype8,
    int* __restrict__ cnt5, int E, int n) {
  int bx = blockIdx.x;
  int range = bx & 7;
  int e = (bx >> 3) * 256 + threadIdx.x;
  if (e >= E) return;
  int per = (n + 7) >> 3;
  int lo = range * per;
  int hi = min(lo + per, n);
  int src = edges[e];
  if (src < lo || src >= hi) return;
  int t = decode_etype(masks, E, e, *flag);
  etype8[e] = (unsigned char)t;
  atomicAdd(&cnt5[src * 8 + t], 1);
}

__global__ __launch_bounds__(256) void scanA5_kernel(const int* __restrict__ cnt5,
                                                     int* __restrict__ loc,
                                                     int* __restrict__ bsums, int n) {
  __shared__ int ts[256];
  int tid = threadIdx.x;
  int i = blockIdx.x * 256 + tid;
  int v = 0;
  if (i < n) {
    int4 c0 = *(const int4*)(cnt5 + (size_t)i * 8);
    v = c0.x + c0.y + c0.z + c0.w + cnt5[(size_t)i * 8 + 4];
  }
  ts[tid] = v;
  __syncthreads();
  for (int o = 1; o < 256; o <<= 1) {
    int t = (tid >= o) ? ts[tid - o] : 0;
    __syncthreads();
    ts[tid] += t;
    __syncthreads();
  }
  if (i < n) loc[i] = ts[tid] - v;
  if (tid == 255) bsums[blockIdx.x] = ts[255];
}

__global__ __launch_bounds__(256) void scanB_kernel(int* __restrict__ bsums, int nb,
                                                    int* __restrict__ total) {
  __shared__ int ts[256];
  int tid = threadIdx.x;
  int per = (nb + 255) / 256;
  int start = tid * per;
  int end = min(start + per, nb);
  int s = 0;
  for (int i = start; i < end; ++i) s += bsums[i];
  ts[tid] = s;
  __syncthreads();
  for (int o = 1; o < 256; o <<= 1) {
    int t = (tid >= o) ? ts[tid - o] : 0;
    __syncthreads();
    ts[tid] += t;
    __syncthreads();
  }
  int run = ts[tid] - s;
  for (int i = start; i < end; ++i) {
    int v = bsums[i];
    bsums[i] = run;
    run += v;
  }
  if (tid == 255) *total = ts[255];
}

// merged scanC+build5
__global__ void build5_kernel(const int* __restrict__ loc,
                              const int* __restrict__ bsums,
                              const int* __restrict__ cnt5,
                              int* __restrict__ cursor5, int* __restrict__ tb,
                              int n) {
  int i = blockIdx.x * 256 + threadIdx.x;
  if (i >= n) return;
  int base = loc[i] + bsums[i >> 8];
#pragma unroll
  for (int t = 0; t < NTYPES; ++t) {
    int c = cnt5[(size_t)i * 8 + t];
    cursor5[(size_t)i * 8 + t] = base;
    tb[(size_t)i * 8 + t] = base;
    base += c;
  }
  tb[(size_t)i * 8 + 5] = base;
}

// fill: range-blocked + XCD-pinned scatter
__global__ __launch_bounds__(256) void fill_kernel(
    const int* __restrict__ edges, const unsigned char* __restrict__ etype8,
    int* __restrict__ cursor5, int* __restrict__ elist, int E, int n) {
  int bx = blockIdx.x;
  int range = bx & 7;
  int e = (bx >> 3) * 256 + threadIdx.x;
  if (e >= E) return;
  int per = (n + 7) >> 3;
  int lo = range * per;
  int hi = min(lo + per, n);
  int src = edges[e];
  if (src < lo || src >= hi) return;
  int t = etype8[e];
  int dst = edges[E + e];
  int pos = atomicAdd(&cursor5[src * 8 + t], 1);
  elist[pos] = t * n + dst;
}

// ---------------------------------------------------------------------------
// K4: per-node attention over type-sorted runs. 16 lanes/node, 4 nodes/wave.
// 4-wide edge pipeline (8 gather rows in flight) + defer-max softmax.
// Tail edges masked branchlessly via p=-1e30 (exact zero contribution).
// ---------------------------------------------------------------------------
__global__ __launch_bounds__(256, 4) void attn_kernel(
    const float* __restrict__ x, const ushort_t* __restrict__ P,
    const int* __restrict__ tb, const int* __restrict__ elist,
    float* __restrict__ out, int n) {
  int node = (blockIdx.x * 256 + threadIdx.x) >> 4;
  int gl = threadIdx.x & 15;
  if (node >= n) return;

  int4 t03 = *(const int4*)(tb + (size_t)node * 8);
  int2 t45 = *(const int2*)(tb + (size_t)node * 8 + 4);
  int bnd0 = t03.x, bnd1 = t03.y, bnd2 = t03.z, bnd3 = t03.w;
  int bnd4 = t45.x, bnd5 = t45.y;

  float m = -1e30f, den = 0.f;
  float a[8];
#pragma unroll
  for (int i = 0; i < 8; ++i) a[i] = 0.f;

#pragma unroll
  for (int t = 0; t < NTYPES; ++t) {
    int jb = (t == 0) ? bnd0 : (t == 1) ? bnd1 : (t == 2) ? bnd2
             : (t == 3) ? bnd3 : bnd4;
    int je = (t == 0) ? bnd1 : (t == 1) ? bnd2 : (t == 2) ? bnd3
             : (t == 3) ? bnd4 : bnd5;
    if (jb >= je) continue;
    bf16x8 qb = *(const bf16x8*)(P + (size_t)(t * n + node) * D + gl * 8);
    float qf[8];
#pragma unroll
    for (int d = 0; d < 8; ++d) qf[d] = (float)qb[d];

    int jlast = je - 1;
    int i1 = (jb + 1 < je) ? jb + 1 : jlast;
    int i2 = (jb + 2 < je) ? jb + 2 : jlast;
    int i3 = (jb + 3 < je) ? jb + 3 : jlast;
    bf16x8 kv0 = *(const bf16x8*)(P + (size_t)elist[jb] * D + gl * 8);
    bf16x8 kv1 = *(const bf16x8*)(P + (size_t)elist[i1] * D + gl * 8);
    bf16x8 kv2 = *(const bf16x8*)(P + (size_t)elist[i2] * D + gl * 8);
    bf16x8 kv3 = *(const bf16x8*)(P + (size_t)elist[i3] * D + gl * 8);

    for (int j = jb; j < je; j += 4) {
      // prefetch quad j+4..j+7 (clamped)
      int jn0 = (j + 4 < je) ? j + 4 : jlast;
      int jn1 = (j + 5 < je) ? j + 5 : jlast;
      int jn2 = (j + 6 < je) ? j + 6 : jlast;
      int jn3 = (j + 7 < je) ? j + 7 : jlast;
      bf16x8 nv0 = *(const bf16x8*)(P + (size_t)elist[jn0] * D + gl * 8);
      bf16x8 nv1 = *(const bf16x8*)(P + (size_t)elist[jn1] * D + gl * 8);
      bf16x8 nv2 = *(const bf16x8*)(P + (size_t)elist[jn2] * D + gl * 8);
      bf16x8 nv3 = *(const bf16x8*)(P + (size_t)elist[jn3] * D + gl * 8);
      // compute quad j..j+3
      float kf0[8], kf1[8], kf2[8], kf3[8];
      float p0 = 0.f, p1 = 0.f, p2 = 0.f, p3 = 0.f;
#pragma unroll
      for (int d = 0; d < 8; ++d) {
        kf0[d] = (float)kv0[d];
        kf1[d] = (float)kv1[d];
        kf2[d] = (float)kv2[d];
        kf3[d] = (float)kv3[d];
        p0 += qf[d] * kf0[d];
        p1 += qf[d] * kf1[d];
        p2 += qf[d] * kf2[d];
        p3 += qf[d] * kf3[d];
      }
      p0 += __shfl_xor(p0, 1);
      p1 += __shfl_xor(p1, 1);
      p2 += __shfl_xor(p2, 1);
      p3 += __shfl_xor(p3, 1);
      p1 = (j + 1 < je) ? p1 : -1e30f;  // tail masks: exact 0 contribution
      p2 = (j + 2 < je) ? p2 : -1e30f;
      p3 = (j + 3 < je) ? p3 : -1e30f;
      float pmax = fmaxf(fmaxf(p0, p1), fmaxf(p2, p3));
      if (pmax > m + 8.f) {
        float sc = __expf(m - pmax);
        den *= sc;
#pragma unroll
        for (int d = 0; d < 8; ++d) a[d] *= sc;
        m = pmax;
      }
      float w0 = __expf(p0 - m);
      float w1 = __expf(p1 - m);
      float w2 = __expf(p2 - m);
      float w3 = __expf(p3 - m);
      den += (w0 + w1) + (w2 + w3);
#pragma unroll
      for (int d = 0; d < 8; ++d)
        a[d] += (w0 * kf0[d] + w1 * kf1[d]) + (w2 * kf2[d] + w3 * kf3[d]);
      kv0 = nv0;
      kv1 = nv1;
      kv2 = nv2;
      kv3 = nv3;
    }
  }

  float inv = (bnd5 > bnd0) ? 1.f / den : 0.f;
  const float* xr = x + (size_t)node * D + gl * 8;
  float* orow = out + (size_t)node * D + gl * 8;
  float4 xa = *(const float4*)xr;
  float4 xb = *(const float4*)(xr + 4);
  float4 oa, ob;
  oa.x = xa.x + a[0] * inv; oa.y = xa.y + a[1] * inv;
  oa.z = xa.z + a[2] * inv; oa.w = xa.w + a[3] * inv;
  ob.x = xb.x + a[4] * inv; ob.y = xb.y + a[5] * inv;
  ob.z = xb.z + a[6] * inv; ob.w = xb.w + a[7] * inv;
  *(float4*)orow = oa;
  *(float4*)(orow + 4) = ob;
}

// ---------------------------------------------------------------------------
// K5: fused LN2 + FFN + residual via MFMA, in-place on out (holds x2).
// 32 rows/block, barrier-free k-split (wave = (r2,ph)), single-term
// activations. Proven R16/R18 body (52.6 µs). FROZEN.
// ---------------------------------------------------------------------------
__global__ __launch_bounds__(256, 4) void ffn_mfma_kernel(
    const ushort_t* __restrict__ w1h, const ushort_t* __restrict__ w2h,
    const float* __restrict__ b1, const float* __restrict__ b2,
    const float* __restrict__ g, const float* __restrict__ bln,
    float* __restrict__ out, int n) {
  __shared__ char smem[16640 + 4 * 2304];
  ushort_t* z2h = (ushort_t*)smem;
  float* red = (float*)smem;
  int tid = threadIdx.x, w = tid >> 6, l = tid & 63;
  int n0 = blockIdx.x * 32;
  int r2 = w & 1, ph = w >> 1;
  float* hbw = (float*)(smem + 16640) + w * 576;

  for (int i = w; i < 32; i += 4) {
    int r = n0 + i;
    float v0 = 0.f, v1 = 0.f;
    if (r < n) {
      v0 = out[(size_t)r * D + l];
      v1 = out[(size_t)r * D + 64 + l];
    }
    float s = v0 + v1, ss = v0 * v0 + v1 * v1;
    for (int o = 32; o; o >>= 1) { s += __shfl_xor(s, o); ss += __shfl_xor(ss, o); }
    float mu = s * (1.f / D);
    float var = ss * (1.f / D) - mu * mu;
    float rs = rsqrtf(var + LN_EPS);
    float z0 = (v0 - mu) * rs * g[l] + bln[l];
    float z1 = (v1 - mu) * rs * g[l + 64] + bln[l + 64];
    int sw = (i & 7) << 3;
    int e0 = (i * D + l) ^ sw;
    int e1 = (i * D + l + 64) ^ sw;
    __bf16 h0 = (__bf16)z0, h1 = (__bf16)z1;
    z2h[e0] = __builtin_bit_cast(ushort_t, h0);
    z2h[e1] = __builtin_bit_cast(ushort_t, h1);
  }
  __syncthreads();

  int lrow = r2 * 16 + (l & 15);
  int koff = (l >> 4) * 8;
  bf16x8 ah[4];
#pragma unroll
  for (int kk = 0; kk < 4; ++kk) {
    int e = (lrow * D + kk * 32 + koff) ^ ((lrow & 7) << 3);
    ah[kk] = *(const bf16x8*)(z2h + e);
  }
  __syncthreads();

  int col16 = l & 15, rgrp = (l >> 4) * 4;
  f32x4 acc2[8];
#pragma unroll
  for (int c = 0; c < 8; ++c) acc2[c] = (f32x4){0.f, 0.f, 0.f, 0.f};

  for (int i = 0; i < 8; ++i) {
    int kk2 = 2 * i + ph;
    bf16x8 B1h[2][4];
#pragma unroll
    for (int cc = 0; cc < 2; ++cc)
#pragma unroll
      for (int kk = 0; kk < 4; ++kk) {
        size_t o = ((size_t)((kk2 * 2 + cc) * 4 + kk) * 64 + l) * 8;
        B1h[cc][kk] = *(const bf16x8*)(w1h + o);
      }
    f32x4 ha[2];
#pragma unroll
    for (int cc = 0; cc < 2; ++cc) {
      float bias = b1[(kk2 * 2 + cc) * 16 + col16];
      ha[cc] = (f32x4){bias, bias, bias, bias};
    }
#pragma unroll
    for (int kk = 0; kk < 4; ++kk)
#pragma unroll
      for (int cc = 0; cc < 2; ++cc)
        ha[cc] = __builtin_amdgcn_mfma_f32_16x16x32_bf16(ah[kk], B1h[cc][kk], ha[cc], 0, 0, 0);
#pragma unroll
    for (int cc = 0; cc < 2; ++cc)
#pragma unroll
      for (int r = 0; r < 4; ++r)
        hbw[(rgrp + r) * 36 + cc * 16 + col16] = fmaxf(ha[cc][r], 0.f);
    float av[8];
    *(float4*)&av[0] = *(const float4*)&hbw[(l & 15) * 36 + koff];
    *(float4*)&av[4] = *(const float4*)&hbw[(l & 15) * 36 + koff + 4];
    bf16x8 a2h;
#pragma unroll
    for (int j = 0; j < 8; ++j) a2h[j] = (__bf16)av[j];
#pragma unroll
    for (int half = 0; half < 2; ++half) {
      bf16x8 B2h[4];
#pragma unroll
      for (int c2 = 0; c2 < 4; ++c2) {
        int ct = half * 4 + c2;
        size_t o = ((size_t)(ct * 16 + kk2) * 64 + l) * 8;
        B2h[c2] = *(const bf16x8*)(w2h + o);
      }
#pragma unroll
      for (int c2 = 0; c2 < 4; ++c2) {
        int ct = half * 4 + c2;
        acc2[ct] = __builtin_amdgcn_mfma_f32_16x16x32_bf16(a2h, B2h[c2], acc2[ct], 0, 0, 0);
      }
    }
  }

  if (ph == 0) {
#pragma unroll
    for (int ct = 0; ct < 8; ++ct)
#pragma unroll
      for (int r = 0; r < 4; ++r)
        red[(r2 * 16 + rgrp + r) * 130 + ct * 16 + col16] = acc2[ct][r];
  }
  __syncthreads();
  if (ph == 1) {
#pragma unroll
    for (int ct = 0; ct < 8; ++ct) {
      int col = ct * 16 + col16;
      float bias2 = b2[col];
#pragma unroll
      for (int r = 0; r < 4; ++r) {
        int row = n0 + r2 * 16 + rgrp + r;
        if (row < n) {
          float part = red[(r2 * 16 + rgrp + r) * 130 + col];
          size_t o = (size_t)row * D + col;
          out[o] = out[o] + acc2[ct][r] + part + bias2;
        }
      }
    }
  }
}

// ---------------------------------------------------------------------------
extern "C" void kernel_launch(void* const* d_in, const int* in_sizes, int n_in,
                              void* d_out, int out_size, void* d_ws, size_t ws_size,
                              hipStream_t stream) {
  const float* x      = (const float*)d_in[0];
  const int* edges    = (const int*)d_in[1];
  const unsigned char* masks = (const unsigned char*)d_in[2];
  const float* Wk     = (const float*)d_in[3];
  const float* bk     = (const float*)d_in[4];
  const float* ln1_g  = (const float*)d_in[5];
  const float* ln1_b  = (const float*)d_in[6];
  const float* ln2_g  = (const float*)d_in[7];
  const float* ln2_b  = (const float*)d_in[8];
  const float* W1     = (const float*)d_in[9];
  const float* b1     = (const float*)d_in[10];
  const float* W2     = (const float*)d_in[11];
  const float* b2     = (const float*)d_in[12];
  float* out = (float*)d_out;

  const int n = in_sizes[0] / D;
  const int E = in_sizes[1] / 2;
  const int nbn = (n + 255) / 256;

  // workspace layout (~74 MB)
  char* ws = (char*)d_ws;
  size_t off = 0;
  ushort_t* P = (ushort_t*)(ws + off);  off += (size_t)NTYPES * n * D * sizeof(ushort_t);
  int* cnt5   = (int*)(ws + off);       off += (size_t)n * 8 * sizeof(int);
  int* cursor5= (int*)(ws + off);       off += (size_t)n * 8 * sizeof(int);
  int* tb     = (int*)(ws + off);       off += (size_t)n * 8 * sizeof(int);
  int* loc    = (int*)(ws + off);       off += (size_t)n * sizeof(int);
  int* bsums  = (int*)(ws + off);       off += (size_t)nbn * sizeof(int);
  int* total  = (int*)(ws + off);       off += 64;
  int* elist  = (int*)(ws + off);       off += (size_t)E * sizeof(int);
  unsigned char* etype8 = (unsigned char*)(ws + off); off += (size_t)E + 64;
  int* flag   = (int*)(ws + off);       off += 64;
  ushort_t* wkh = (ushort_t*)(ws + off); off += (size_t)NTYPES * D * D * sizeof(ushort_t);
  ushort_t* w1h = (ushort_t*)(ws + off); off += (size_t)D * FFDIM * sizeof(ushort_t);
  ushort_t* w2h = (ushort_t*)(ws + off); off += (size_t)FFDIM * D * sizeof(ushort_t);
  (void)ws_size; (void)n_in; (void)out_size;

  // K0: mask dtype detection
  detect_kernel<<<1, 64, 0, stream>>>(masks, E, flag);

  // K1b: weight fragment conversion (hi only)
  {
    dim3 gwk((8 * 4 * 64 + 255) / 256, NTYPES);
    conv_frag_kernel<<<gwk, 256, 0, stream>>>(Wk, wkh, D, D,
                                              (size_t)D * D, (size_t)D * D);
    dim3 gw1(((FFDIM / 16) * 4 * 64 + 255) / 256, 1);
    conv_frag_kernel<<<gw1, 256, 0, stream>>>(W1, w1h, D, FFDIM, 0, 0);
    dim3 gw2((8 * (FFDIM / 32) * 64 + 255) / 256, 1);
    conv_frag_kernel<<<gw2, 256, 0, stream>>>(W2, w2h, FFDIM, D, 0, 0);
  }

  // K2: fused LN1 + projections
  projln_kernel<<<(n + 63) / 64, 256, 0, stream>>>(x, ln1_g, ln1_b, wkh, bk, P, n);

  // K3: typed-CSR build (etype decode fused into hist5)
  zero_kernel<<<(n * 8 + 255) / 256, 256, 0, stream>>>(cnt5, n * 8);
  hist5_kernel<<<((E + 255) / 256) * 8, 256, 0, stream>>>(edges, masks, flag,
                                                          etype8, cnt5, E, n);
  scanA5_kernel<<<nbn, 256, 0, stream>>>(cnt5, loc, bsums, n);
  scanB_kernel<<<1, 256, 0, stream>>>(bsums, nbn, total);
  build5_kernel<<<(n + 255) / 256, 256, 0, stream>>>(loc, bsums, cnt5, cursor5, tb, n);
  fill_kernel<<<((E + 255) / 256) * 8, 256, 0, stream>>>(edges, etype8, cursor5,
                                                         elist, E, n);

  // K4: attention -> out = x + attn (4-wide edge pipeline)
  attn_kernel<<<(n + 15) / 16, 256, 0, stream>>>(x, P, tb, elist, out, n);

  // K5: LN2 + FFN + residual (32 rows/block, barrier-free k-split)
  ffn_mfma_kernel<<<(n + 31) / 32, 256, 0, stream>>>(w1h, w2h,
                                                     b1, b2, ln2_g, ln2_b, out, n);
}

// Round 22
// 234.106 us; speedup vs baseline: 1.0159x; 1.0159x over previous
//
#include <hip/hip_runtime.h>

// Problem constants (match reference)
#define D 128
#define H 8
#define DK 16
#define FFDIM 512
#define NTYPES 5
#define LN_EPS 1e-5f

typedef __bf16 bf16x8 __attribute__((ext_vector_type(8)));
typedef float f32x4 __attribute__((ext_vector_type(4)));
typedef unsigned short ushort_t;
typedef unsigned int uint_t;

__device__ inline ushort_t bfbits(float f) {
  __bf16 b = (__bf16)f;
  return __builtin_bit_cast(ushort_t, b);
}

// ---------------------------------------------------------------------------
// K0: detect mask dtype (byte-bool vs int32). flag=1 for byte masks.
// ---------------------------------------------------------------------------
__global__ void detect_kernel(const unsigned char* __restrict__ m8, int E,
                              int* __restrict__ flag) {
  int lane = threadIdx.x;  // 64 threads, 1 wave
  int s = 1;
  if (lane < E) {
    s = 0;
#pragma unroll
    for (int i = 0; i < NTYPES; ++i) s += (m8[(size_t)i * E + lane] != 0);
  }
  unsigned long long b = __ballot(s == 1);
  if (lane == 0) *flag = (b == ~0ull) ? 1 : 0;
}

__device__ inline int decode_etype(const unsigned char* __restrict__ m8,
                                   int E, int e, int is8) {
  int t = 0;
  if (is8) {
#pragma unroll
    for (int i = 1; i < NTYPES; ++i) t += i * (m8[(size_t)i * E + e] != 0);
  } else {
    const int* m32 = (const int*)m8;
#pragma unroll
    for (int i = 1; i < NTYPES; ++i) t += i * (m32[(size_t)i * E + e] != 0);
  }
  return t > (NTYPES - 1) ? (NTYPES - 1) : t;
}

// ---------------------------------------------------------------------------
// K1b: convert a row-major f32 weight [K][N] into MFMA B-fragment order, bf16 hi.
// ---------------------------------------------------------------------------
__global__ void conv_frag_kernel(const float* __restrict__ W,
                                 ushort_t* __restrict__ hi,
                                 int K, int Ncol, size_t matW, size_t matF) {
  int gid = blockIdx.x * 256 + threadIdx.x;
  int total = (Ncol / 16) * (K / 32) * 64;
  if (gid >= total) return;
  const float* Wm = W + (size_t)blockIdx.y * matW;
  ushort_t* him = hi + (size_t)blockIdx.y * matF;
  int l = gid & 63;
  int ck = gid >> 6;
  int kk = ck % (K / 32);
  int c = ck / (K / 32);
  int row0 = kk * 32 + (l >> 4) * 8;
  int col = c * 16 + (l & 15);
  size_t ob = (size_t)gid * 8;
#pragma unroll
  for (int j = 0; j < 8; ++j) {
    float w = Wm[(size_t)(row0 + j) * Ncol + col];
    __bf16 h = (__bf16)w;
    him[ob + j] = __builtin_bit_cast(ushort_t, h);
  }
}

// ---------------------------------------------------------------------------
// K2: fused LN1 + proj via MFMA. 64 rows/block, 4 waves. z hi/lo split.
// ---------------------------------------------------------------------------
__global__ __launch_bounds__(256, 4) void projln_kernel(
    const float* __restrict__ x, const float* __restrict__ g,
    const float* __restrict__ b, const ushort_t* __restrict__ wkh,
    const float* __restrict__ bk, ushort_t* __restrict__ P, int n) {
  __shared__ ushort_t zsh[64 * D];
  __shared__ ushort_t zsl[64 * D];
  int tid = threadIdx.x, w = tid >> 6, l = tid & 63;
  int n0 = blockIdx.x * 64;

  for (int i = w; i < 64; i += 4) {
    int r = n0 + i;
    float v0 = 0.f, v1 = 0.f;
    if (r < n) {
      v0 = x[(size_t)r * D + l];
      v1 = x[(size_t)r * D + 64 + l];
    }
    float s = v0 + v1, ss = v0 * v0 + v1 * v1;
    for (int o = 32; o; o >>= 1) { s += __shfl_xor(s, o); ss += __shfl_xor(ss, o); }
    float mu = s * (1.f / D);
    float var = ss * (1.f / D) - mu * mu;
    float rs = rsqrtf(var + LN_EPS);
    float z0 = (v0 - mu) * rs * g[l] + b[l];
    float z1 = (v1 - mu) * rs * g[l + 64] + b[l + 64];
    int sw = (i & 7) << 3;
    int e0 = (i * D + l) ^ sw;
    int e1 = (i * D + l + 64) ^ sw;
    __bf16 h0 = (__bf16)z0, h1 = (__bf16)z1;
    zsh[e0] = __builtin_bit_cast(ushort_t, h0);
    zsh[e1] = __builtin_bit_cast(ushort_t, h1);
    __bf16 l0 = (__bf16)(z0 - (float)h0), l1 = (__bf16)(z1 - (float)h1);
    zsl[e0] = __builtin_bit_cast(ushort_t, l0);
    zsl[e1] = __builtin_bit_cast(ushort_t, l1);
  }
  __syncthreads();

  int lrow = w * 16 + (l & 15);
  int koff = (l >> 4) * 8;
  bf16x8 ah[4], al[4];
#pragma unroll
  for (int kk = 0; kk < 4; ++kk) {
    int e = (lrow * D + kk * 32 + koff) ^ ((lrow & 7) << 3);
    ah[kk] = *(const bf16x8*)(zsh + e);
    al[kk] = *(const bf16x8*)(zsl + e);
  }

  int col16 = l & 15, rgrp = (l >> 4) * 4;
  int rowbase = n0 + w * 16;
  for (int t = 0; t < NTYPES; ++t) {
    const ushort_t* bh0 = wkh + (size_t)t * (D * D);
    ushort_t* Pt = P + (size_t)t * n * D;
#pragma unroll
    for (int cp = 0; cp < 4; ++cp) {
      bf16x8 Bh[2][4];
#pragma unroll
      for (int cc = 0; cc < 2; ++cc)
#pragma unroll
        for (int kk = 0; kk < 4; ++kk) {
          size_t o = ((size_t)((cp * 2 + cc) * 4 + kk) * 64 + l) * 8;
          Bh[cc][kk] = *(const bf16x8*)(bh0 + o);
        }
      f32x4 aa[2], ac[2];
#pragma unroll
      for (int cc = 0; cc < 2; ++cc) {
        float bias = bk[t * D + (cp * 2 + cc) * 16 + col16];
        aa[cc] = (f32x4){bias, bias, bias, bias};
        ac[cc] = (f32x4){0.f, 0.f, 0.f, 0.f};
      }
#pragma unroll
      for (int kk = 0; kk < 4; ++kk)
#pragma unroll
        for (int cc = 0; cc < 2; ++cc) {
          aa[cc] = __builtin_amdgcn_mfma_f32_16x16x32_bf16(ah[kk], Bh[cc][kk], aa[cc], 0, 0, 0);
          ac[cc] = __builtin_amdgcn_mfma_f32_16x16x32_bf16(al[kk], Bh[cc][kk], ac[cc], 0, 0, 0);
        }
#pragma unroll
      for (int cc = 0; cc < 2; ++cc)
#pragma unroll
        for (int r = 0; r < 4; ++r) {
          int row = rowbase + rgrp + r;
          if (row < n)
            Pt[(size_t)row * D + (cp * 2 + cc) * 16 + col16] =
                bfbits(aa[cc][r] + ac[cc][r]);
        }
    }
  }
}

// ---------------------------------------------------------------------------
// K3: typed-CSR build by (src, etype)
// ---------------------------------------------------------------------------
__global__ void zero_kernel(int* __restrict__ p, int n) {
  int i = blockIdx.x * 256 + threadIdx.x;
  if (i < n) p[i] = 0;
}

// range-blocked + XCD-pinned histogram with inline etype decode
__global__ __launch_bounds__(256) void hist5_kernel(
    const int* __restrict__ edges, const unsigned char* __restrict__ masks,
    const int* __restrict__ flag, unsigned char* __restrict__ etype8,
    int* __restrict__ cnt5, int E, int n) {
  int bx = blockIdx.x;
  int range = bx & 7;
  int e = (bx >> 3) * 256 + threadIdx.x;
  if (e >= E) return;
  int per = (n + 7) >> 3;
  int lo = range * per;
  int hi = min(lo + per, n);
  int src = edges[e];
  if (src < lo || src >= hi) return;
  int t = decode_etype(masks, E, e, *flag);
  etype8[e] = (unsigned char)t;
  atomicAdd(&cnt5[src * 8 + t], 1);
}

__global__ __launch_bounds__(256) void scanA5_kernel(const int* __restrict__ cnt5,
                                                     int* __restrict__ loc,
                                                     int* __restrict__ bsums, int n) {
  __shared__ int ts[256];
  int tid = threadIdx.x;
  int i = blockIdx.x * 256 + tid;
  int v = 0;
  if (i < n) {
    int4 c0 = *(const int4*)(cnt5 + (size_t)i * 8);
    v = c0.x + c0.y + c0.z + c0.w + cnt5[(size_t)i * 8 + 4];
  }
  ts[tid] = v;
  __syncthreads();
  for (int o = 1; o < 256; o <<= 1) {
    int t = (tid >= o) ? ts[tid - o] : 0;
    __syncthreads();
    ts[tid] += t;
    __syncthreads();
  }
  if (i < n) loc[i] = ts[tid] - v;
  if (tid == 255) bsums[blockIdx.x] = ts[255];
}

__global__ __launch_bounds__(256) void scanB_kernel(int* __restrict__ bsums, int nb,
                                                    int* __restrict__ total) {
  __shared__ int ts[256];
  int tid = threadIdx.x;
  int per = (nb + 255) / 256;
  int start = tid * per;
  int end = min(start + per, nb);
  int s = 0;
  for (int i = start; i < end; ++i) s += bsums[i];
  ts[tid] = s;
  __syncthreads();
  for (int o = 1; o < 256; o <<= 1) {
    int t = (tid >= o) ? ts[tid - o] : 0;
    __syncthreads();
    ts[tid] += t;
    __syncthreads();
  }
  int run = ts[tid] - s;
  for (int i = start; i < end; ++i) {
    int v = bsums[i];
    bsums[i] = run;
    run += v;
  }
  if (tid == 255) *total = ts[255];
}

// merged scanC+build5
__global__ void build5_kernel(const int* __restrict__ loc,
                              const int* __restrict__ bsums,
                              const int* __restrict__ cnt5,
                              int* __restrict__ cursor5, int* __restrict__ tb,
                              int n) {
  int i = blockIdx.x * 256 + threadIdx.x;
  if (i >= n) return;
  int base = loc[i] + bsums[i >> 8];
#pragma unroll
  for (int t = 0; t < NTYPES; ++t) {
    int c = cnt5[(size_t)i * 8 + t];
    cursor5[(size_t)i * 8 + t] = base;
    tb[(size_t)i * 8 + t] = base;
    base += c;
  }
  tb[(size_t)i * 8 + 5] = base;
}

// fill: range-blocked + XCD-pinned scatter
__global__ __launch_bounds__(256) void fill_kernel(
    const int* __restrict__ edges, const unsigned char* __restrict__ etype8,
    int* __restrict__ cursor5, int* __restrict__ elist, int E, int n) {
  int bx = blockIdx.x;
  int range = bx & 7;
  int e = (bx >> 3) * 256 + threadIdx.x;
  if (e >= E) return;
  int per = (n + 7) >> 3;
  int lo = range * per;
  int hi = min(lo + per, n);
  int src = edges[e];
  if (src < lo || src >= hi) return;
  int t = etype8[e];
  int dst = edges[E + e];
  int pos = atomicAdd(&cursor5[src * 8 + t], 1);
  elist[pos] = t * n + dst;
}

// ---------------------------------------------------------------------------
// K4: per-node attention over type-sorted runs. 16 lanes/node, 4 nodes/wave.
// 2-wide edge pipeline (4 gather rows in flight) + defer-max softmax.
// (4-wide was tried and regressed: VALU-bound + occupancy drop. FROZEN.)
// ---------------------------------------------------------------------------
__global__ __launch_bounds__(256, 4) void attn_kernel(
    const float* __restrict__ x, const ushort_t* __restrict__ P,
    const int* __restrict__ tb, const int* __restrict__ elist,
    float* __restrict__ out, int n) {
  int node = (blockIdx.x * 256 + threadIdx.x) >> 4;
  int gl = threadIdx.x & 15;
  if (node >= n) return;

  int4 t03 = *(const int4*)(tb + (size_t)node * 8);
  int2 t45 = *(const int2*)(tb + (size_t)node * 8 + 4);
  int bnd0 = t03.x, bnd1 = t03.y, bnd2 = t03.z, bnd3 = t03.w;
  int bnd4 = t45.x, bnd5 = t45.y;

  float m = -1e30f, den = 0.f;
  float a[8];
#pragma unroll
  for (int i = 0; i < 8; ++i) a[i] = 0.f;

#pragma unroll
  for (int t = 0; t < NTYPES; ++t) {
    int jb = (t == 0) ? bnd0 : (t == 1) ? bnd1 : (t == 2) ? bnd2
             : (t == 3) ? bnd3 : bnd4;
    int je = (t == 0) ? bnd1 : (t == 1) ? bnd2 : (t == 2) ? bnd3
             : (t == 3) ? bnd4 : bnd5;
    if (jb >= je) continue;
    bf16x8 qb = *(const bf16x8*)(P + (size_t)(t * n + node) * D + gl * 8);
    float qf[8];
#pragma unroll
    for (int d = 0; d < 8; ++d) qf[d] = (float)qb[d];

    int jlast = je - 1;
    bf16x8 kv0 = *(const bf16x8*)(P + (size_t)elist[jb] * D + gl * 8);
    int j1 = (jb + 1 < je) ? jb + 1 : jlast;
    bf16x8 kv1 = *(const bf16x8*)(P + (size_t)elist[j1] * D + gl * 8);

    for (int j = jb; j < je; j += 2) {
      int jn0 = (j + 2 < je) ? j + 2 : jlast;
      int jn1 = (j + 3 < je) ? j + 3 : jlast;
      bf16x8 nv0 = *(const bf16x8*)(P + (size_t)elist[jn0] * D + gl * 8);
      bf16x8 nv1 = *(const bf16x8*)(P + (size_t)elist[jn1] * D + gl * 8);
      float kf0[8], kf1[8], p0 = 0.f, p1 = 0.f;
#pragma unroll
      for (int d = 0; d < 8; ++d) {
        kf0[d] = (float)kv0[d];
        kf1[d] = (float)kv1[d];
        p0 += qf[d] * kf0[d];
        p1 += qf[d] * kf1[d];
      }
      p0 += __shfl_xor(p0, 1);
      p1 += __shfl_xor(p1, 1);
      p1 = (j + 1 < je) ? p1 : -1e30f;  // tail mask: exact 0 contribution
      float pmax = fmaxf(p0, p1);
      if (pmax > m + 8.f) {
        float sc = __expf(m - pmax);
        den *= sc;
#pragma unroll
        for (int d = 0; d < 8; ++d) a[d] *= sc;
        m = pmax;
      }
      float w0 = __expf(p0 - m);
      float w1 = __expf(p1 - m);
      den += w0 + w1;
#pragma unroll
      for (int d = 0; d < 8; ++d) a[d] += w0 * kf0[d] + w1 * kf1[d];
      kv0 = nv0;
      kv1 = nv1;
    }
  }

  float inv = (bnd5 > bnd0) ? 1.f / den : 0.f;
  const float* xr = x + (size_t)node * D + gl * 8;
  float* orow = out + (size_t)node * D + gl * 8;
  float4 xa = *(const float4*)xr;
  float4 xb = *(const float4*)(xr + 4);
  float4 oa, ob;
  oa.x = xa.x + a[0] * inv; oa.y = xa.y + a[1] * inv;
  oa.z = xa.z + a[2] * inv; oa.w = xa.w + a[3] * inv;
  ob.x = xb.x + a[4] * inv; ob.y = xb.y + a[5] * inv;
  ob.z = xb.z + a[6] * inv; ob.w = xb.w + a[7] * inv;
  *(float4*)orow = oa;
  *(float4*)(orow + 4) = ob;
}

// ---------------------------------------------------------------------------
// K5: fused LN2 + FFN + residual via MFMA, in-place on out (holds x2).
// 32 rows/block, barrier-free k-split (wave = (r2,ph)), single-term
// activations. Proven body (52.6 µs). FROZEN.
// ---------------------------------------------------------------------------
__global__ __launch_bounds__(256, 4) void ffn_mfma_kernel(
    const ushort_t* __restrict__ w1h, const ushort_t* __restrict__ w2h,
    const float* __restrict__ b1, const float* __restrict__ b2,
    const float* __restrict__ g, const float* __restrict__ bln,
    float* __restrict__ out, int n) {
  __shared__ char smem[16640 + 4 * 2304];
  ushort_t* z2h = (ushort_t*)smem;
  float* red = (float*)smem;
  int tid = threadIdx.x, w = tid >> 6, l = tid & 63;
  int n0 = blockIdx.x * 32;
  int r2 = w & 1, ph = w >> 1;
  float* hbw = (float*)(smem + 16640) + w * 576;

  for (int i = w; i < 32; i += 4) {
    int r = n0 + i;
    float v0 = 0.f, v1 = 0.f;
    if (r < n) {
      v0 = out[(size_t)r * D + l];
      v1 = out[(size_t)r * D + 64 + l];
    }
    float s = v0 + v1, ss = v0 * v0 + v1 * v1;
    for (int o = 32; o; o >>= 1) { s += __shfl_xor(s, o); ss += __shfl_xor(ss, o); }
    float mu = s * (1.f / D);
    float var = ss * (1.f / D) - mu * mu;
    float rs = rsqrtf(var + LN_EPS);
    float z0 = (v0 - mu) * rs * g[l] + bln[l];
    float z1 = (v1 - mu) * rs * g[l + 64] + bln[l + 64];
    int sw = (i & 7) << 3;
    int e0 = (i * D + l) ^ sw;
    int e1 = (i * D + l + 64) ^ sw;
    __bf16 h0 = (__bf16)z0, h1 = (__bf16)z1;
    z2h[e0] = __builtin_bit_cast(ushort_t, h0);
    z2h[e1] = __builtin_bit_cast(ushort_t, h1);
  }
  __syncthreads();

  int lrow = r2 * 16 + (l & 15);
  int koff = (l >> 4) * 8;
  bf16x8 ah[4];
#pragma unroll
  for (int kk = 0; kk < 4; ++kk) {
    int e = (lrow * D + kk * 32 + koff) ^ ((lrow & 7) << 3);
    ah[kk] = *(const bf16x8*)(z2h + e);
  }
  __syncthreads();

  int col16 = l & 15, rgrp = (l >> 4) * 4;
  f32x4 acc2[8];
#pragma unroll
  for (int c = 0; c < 8; ++c) acc2[c] = (f32x4){0.f, 0.f, 0.f, 0.f};

  for (int i = 0; i < 8; ++i) {
    int kk2 = 2 * i + ph;
    bf16x8 B1h[2][4];
#pragma unroll
    for (int cc = 0; cc < 2; ++cc)
#pragma unroll
      for (int kk = 0; kk < 4; ++kk) {
        size_t o = ((size_t)((kk2 * 2 + cc) * 4 + kk) * 64 + l) * 8;
        B1h[cc][kk] = *(const bf16x8*)(w1h + o);
      }
    f32x4 ha[2];
#pragma unroll
    for (int cc = 0; cc < 2; ++cc) {
      float bias = b1[(kk2 * 2 + cc) * 16 + col16];
      ha[cc] = (f32x4){bias, bias, bias, bias};
    }
#pragma unroll
    for (int kk = 0; kk < 4; ++kk)
#pragma unroll
      for (int cc = 0; cc < 2; ++cc)
        ha[cc] = __builtin_amdgcn_mfma_f32_16x16x32_bf16(ah[kk], B1h[cc][kk], ha[cc], 0, 0, 0);
#pragma unroll
    for (int cc = 0; cc < 2; ++cc)
#pragma unroll
      for (int r = 0; r < 4; ++r)
        hbw[(rgrp + r) * 36 + cc * 16 + col16] = fmaxf(ha[cc][r], 0.f);
    float av[8];
    *(float4*)&av[0] = *(const float4*)&hbw[(l & 15) * 36 + koff];
    *(float4*)&av[4] = *(const float4*)&hbw[(l & 15) * 36 + koff + 4];
    bf16x8 a2h;
#pragma unroll
    for (int j = 0; j < 8; ++j) a2h[j] = (__bf16)av[j];
#pragma unroll
    for (int half = 0; half < 2; ++half) {
      bf16x8 B2h[4];
#pragma unroll
      for (int c2 = 0; c2 < 4; ++c2) {
        int ct = half * 4 + c2;
        size_t o = ((size_t)(ct * 16 + kk2) * 64 + l) * 8;
        B2h[c2] = *(const bf16x8*)(w2h + o);
      }
#pragma unroll
      for (int c2 = 0; c2 < 4; ++c2) {
        int ct = half * 4 + c2;
        acc2[ct] = __builtin_amdgcn_mfma_f32_16x16x32_bf16(a2h, B2h[c2], acc2[ct], 0, 0, 0);
      }
    }
  }

  if (ph == 0) {
#pragma unroll
    for (int ct = 0; ct < 8; ++ct)
#pragma unroll
      for (int r = 0; r < 4; ++r)
        red[(r2 * 16 + rgrp + r) * 130 + ct * 16 + col16] = acc2[ct][r];
  }
  __syncthreads();
  if (ph == 1) {
#pragma unroll
    for (int ct = 0; ct < 8; ++ct) {
      int col = ct * 16 + col16;
      float bias2 = b2[col];
#pragma unroll
      for (int r = 0; r < 4; ++r) {
        int row = n0 + r2 * 16 + rgrp + r;
        if (row < n) {
          float part = red[(r2 * 16 + rgrp + r) * 130 + col];
          size_t o = (size_t)row * D + col;
          out[o] = out[o] + acc2[ct][r] + part + bias2;
        }
      }
    }
  }
}

// ---------------------------------------------------------------------------
extern "C" void kernel_launch(void* const* d_in, const int* in_sizes, int n_in,
                              void* d_out, int out_size, void* d_ws, size_t ws_size,
                              hipStream_t stream) {
  const float* x      = (const float*)d_in[0];
  const int* edges    = (const int*)d_in[1];
  const unsigned char* masks = (const unsigned char*)d_in[2];
  const float* Wk     = (const float*)d_in[3];
  const float* bk     = (const float*)d_in[4];
  const float* ln1_g  = (const float*)d_in[5];
  const float* ln1_b  = (const float*)d_in[6];
  const float* ln2_g  = (const float*)d_in[7];
  const float* ln2_b  = (const float*)d_in[8];
  const float* W1     = (const float*)d_in[9];
  const float* b1     = (const float*)d_in[10];
  const float* W2     = (const float*)d_in[11];
  const float* b2     = (const float*)d_in[12];
  float* out = (float*)d_out;

  const int n = in_sizes[0] / D;
  const int E = in_sizes[1] / 2;
  const int nbn = (n + 255) / 256;

  // workspace layout (~74 MB)
  char* ws = (char*)d_ws;
  size_t off = 0;
  ushort_t* P = (ushort_t*)(ws + off);  off += (size_t)NTYPES * n * D * sizeof(ushort_t);
  int* cnt5   = (int*)(ws + off);       off += (size_t)n * 8 * sizeof(int);
  int* cursor5= (int*)(ws + off);       off += (size_t)n * 8 * sizeof(int);
  int* tb     = (int*)(ws + off);       off += (size_t)n * 8 * sizeof(int);
  int* loc    = (int*)(ws + off);       off += (size_t)n * sizeof(int);
  int* bsums  = (int*)(ws + off);       off += (size_t)nbn * sizeof(int);
  int* total  = (int*)(ws + off);       off += 64;
  int* elist  = (int*)(ws + off);       off += (size_t)E * sizeof(int);
  unsigned char* etype8 = (unsigned char*)(ws + off); off += (size_t)E + 64;
  int* flag   = (int*)(ws + off);       off += 64;
  ushort_t* wkh = (ushort_t*)(ws + off); off += (size_t)NTYPES * D * D * sizeof(ushort_t);
  ushort_t* w1h = (ushort_t*)(ws + off); off += (size_t)D * FFDIM * sizeof(ushort_t);
  ushort_t* w2h = (ushort_t*)(ws + off); off += (size_t)FFDIM * D * sizeof(ushort_t);
  (void)ws_size; (void)n_in; (void)out_size;

  // K0: mask dtype detection
  detect_kernel<<<1, 64, 0, stream>>>(masks, E, flag);

  // K1b: weight fragment conversion (hi only)
  {
    dim3 gwk((8 * 4 * 64 + 255) / 256, NTYPES);
    conv_frag_kernel<<<gwk, 256, 0, stream>>>(Wk, wkh, D, D,
                                              (size_t)D * D, (size_t)D * D);
    dim3 gw1(((FFDIM / 16) * 4 * 64 + 255) / 256, 1);
    conv_frag_kernel<<<gw1, 256, 0, stream>>>(W1, w1h, D, FFDIM, 0, 0);
    dim3 gw2((8 * (FFDIM / 32) * 64 + 255) / 256, 1);
    conv_frag_kernel<<<gw2, 256, 0, stream>>>(W2, w2h, FFDIM, D, 0, 0);
  }

  // K2: fused LN1 + projections
  projln_kernel<<<(n + 63) / 64, 256, 0, stream>>>(x, ln1_g, ln1_b, wkh, bk, P, n);

  // K3: typed-CSR build (etype decode fused into hist5)
  zero_kernel<<<(n * 8 + 255) / 256, 256, 0, stream>>>(cnt5, n * 8);
  hist5_kernel<<<((E + 255) / 256) * 8, 256, 0, stream>>>(edges, masks, flag,
                                                          etype8, cnt5, E, n);
  scanA5_kernel<<<nbn, 256, 0, stream>>>(cnt5, loc, bsums, n);
  scanB_kernel<<<1, 256, 0, stream>>>(bsums, nbn, total);
  build5_kernel<<<(n + 255) / 256, 256, 0, stream>>>(loc, bsums, cnt5, cursor5, tb, n);
  fill_kernel<<<((E + 255) / 256) * 8, 256, 0, stream>>>(edges, etype8, cursor5,
                                                         elist, E, n);

  // K4: attention -> out = x + attn (2-wide edge pipeline)
  attn_kernel<<<(n + 15) / 16, 256, 0, stream>>>(x, P, tb, elist, out, n);

  // K5: LN2 + FFN + residual (32 rows/block, barrier-free k-split)
  ffn_mfma_kernel<<<(n + 31) / 32, 256, 0, stream>>>(w1h, w2h,
                                                     b1, b2, ln2_g, ln2_b, out, n);
}

// Round 23
// 233.241 us; speedup vs baseline: 1.0196x; 1.0037x over previous
//
#include <hip/hip_runtime.h>

// Problem constants (match reference)
#define D 128
#define H 8
#define DK 16
#define FFDIM 512
#define NTYPES 5
#define LN_EPS 1e-5f

typedef __bf16 bf16x8 __attribute__((ext_vector_type(8)));
typedef float f32x4 __attribute__((ext_vector_type(4)));
typedef unsigned short ushort_t;
typedef unsigned int uint_t;

__device__ inline ushort_t bfbits(float f) {
  __bf16 b = (__bf16)f;
  return __builtin_bit_cast(ushort_t, b);
}

// ---------------------------------------------------------------------------
// K0: detect mask dtype (byte-bool vs int32). flag=1 for byte masks.
// ---------------------------------------------------------------------------
__global__ void detect_kernel(const unsigned char* __restrict__ m8, int E,
                              int* __restrict__ flag) {
  int lane = threadIdx.x;  // 64 threads, 1 wave
  int s = 1;
  if (lane < E) {
    s = 0;
#pragma unroll
    for (int i = 0; i < NTYPES; ++i) s += (m8[(size_t)i * E + lane] != 0);
  }
  unsigned long long b = __ballot(s == 1);
  if (lane == 0) *flag = (b == ~0ull) ? 1 : 0;
}

__device__ inline int decode_etype(const unsigned char* __restrict__ m8,
                                   int E, int e, int is8) {
  int t = 0;
  if (is8) {
#pragma unroll
    for (int i = 1; i < NTYPES; ++i) t += i * (m8[(size_t)i * E + e] != 0);
  } else {
    const int* m32 = (const int*)m8;
#pragma unroll
    for (int i = 1; i < NTYPES; ++i) t += i * (m32[(size_t)i * E + e] != 0);
  }
  return t > (NTYPES - 1) ? (NTYPES - 1) : t;
}

// ---------------------------------------------------------------------------
// K1b: convert a row-major f32 weight [K][N] into MFMA B-fragment order, bf16 hi.
// ---------------------------------------------------------------------------
__global__ void conv_frag_kernel(const float* __restrict__ W,
                                 ushort_t* __restrict__ hi,
                                 int K, int Ncol, size_t matW, size_t matF) {
  int gid = blockIdx.x * 256 + threadIdx.x;
  int total = (Ncol / 16) * (K / 32) * 64;
  if (gid >= total) return;
  const float* Wm = W + (size_t)blockIdx.y * matW;
  ushort_t* him = hi + (size_t)blockIdx.y * matF;
  int l = gid & 63;
  int ck = gid >> 6;
  int kk = ck % (K / 32);
  int c = ck / (K / 32);
  int row0 = kk * 32 + (l >> 4) * 8;
  int col = c * 16 + (l & 15);
  size_t ob = (size_t)gid * 8;
#pragma unroll
  for (int j = 0; j < 8; ++j) {
    float w = Wm[(size_t)(row0 + j) * Ncol + col];
    __bf16 h = (__bf16)w;
    him[ob + j] = __builtin_bit_cast(ushort_t, h);
  }
}

// ---------------------------------------------------------------------------
// K2: fused LN1 + proj via MFMA. 64 rows/block, 4 waves. z hi/lo split.
// ---------------------------------------------------------------------------
__global__ __launch_bounds__(256, 4) void projln_kernel(
    const float* __restrict__ x, const float* __restrict__ g,
    const float* __restrict__ b, const ushort_t* __restrict__ wkh,
    const float* __restrict__ bk, ushort_t* __restrict__ P, int n) {
  __shared__ ushort_t zsh[64 * D];
  __shared__ ushort_t zsl[64 * D];
  int tid = threadIdx.x, w = tid >> 6, l = tid & 63;
  int n0 = blockIdx.x * 64;

  for (int i = w; i < 64; i += 4) {
    int r = n0 + i;
    float v0 = 0.f, v1 = 0.f;
    if (r < n) {
      v0 = x[(size_t)r * D + l];
      v1 = x[(size_t)r * D + 64 + l];
    }
    float s = v0 + v1, ss = v0 * v0 + v1 * v1;
    for (int o = 32; o; o >>= 1) { s += __shfl_xor(s, o); ss += __shfl_xor(ss, o); }
    float mu = s * (1.f / D);
    float var = ss * (1.f / D) - mu * mu;
    float rs = rsqrtf(var + LN_EPS);
    float z0 = (v0 - mu) * rs * g[l] + b[l];
    float z1 = (v1 - mu) * rs * g[l + 64] + b[l + 64];
    int sw = (i & 7) << 3;
    int e0 = (i * D + l) ^ sw;
    int e1 = (i * D + l + 64) ^ sw;
    __bf16 h0 = (__bf16)z0, h1 = (__bf16)z1;
    zsh[e0] = __builtin_bit_cast(ushort_t, h0);
    zsh[e1] = __builtin_bit_cast(ushort_t, h1);
    __bf16 l0 = (__bf16)(z0 - (float)h0), l1 = (__bf16)(z1 - (float)h1);
    zsl[e0] = __builtin_bit_cast(ushort_t, l0);
    zsl[e1] = __builtin_bit_cast(ushort_t, l1);
  }
  __syncthreads();

  int lrow = w * 16 + (l & 15);
  int koff = (l >> 4) * 8;
  bf16x8 ah[4], al[4];
#pragma unroll
  for (int kk = 0; kk < 4; ++kk) {
    int e = (lrow * D + kk * 32 + koff) ^ ((lrow & 7) << 3);
    ah[kk] = *(const bf16x8*)(zsh + e);
    al[kk] = *(const bf16x8*)(zsl + e);
  }

  int col16 = l & 15, rgrp = (l >> 4) * 4;
  int rowbase = n0 + w * 16;
  for (int t = 0; t < NTYPES; ++t) {
    const ushort_t* bh0 = wkh + (size_t)t * (D * D);
    ushort_t* Pt = P + (size_t)t * n * D;
#pragma unroll
    for (int cp = 0; cp < 4; ++cp) {
      bf16x8 Bh[2][4];
#pragma unroll
      for (int cc = 0; cc < 2; ++cc)
#pragma unroll
        for (int kk = 0; kk < 4; ++kk) {
          size_t o = ((size_t)((cp * 2 + cc) * 4 + kk) * 64 + l) * 8;
          Bh[cc][kk] = *(const bf16x8*)(bh0 + o);
        }
      f32x4 aa[2], ac[2];
#pragma unroll
      for (int cc = 0; cc < 2; ++cc) {
        float bias = bk[t * D + (cp * 2 + cc) * 16 + col16];
        aa[cc] = (f32x4){bias, bias, bias, bias};
        ac[cc] = (f32x4){0.f, 0.f, 0.f, 0.f};
      }
#pragma unroll
      for (int kk = 0; kk < 4; ++kk)
#pragma unroll
        for (int cc = 0; cc < 2; ++cc) {
          aa[cc] = __builtin_amdgcn_mfma_f32_16x16x32_bf16(ah[kk], Bh[cc][kk], aa[cc], 0, 0, 0);
          ac[cc] = __builtin_amdgcn_mfma_f32_16x16x32_bf16(al[kk], Bh[cc][kk], ac[cc], 0, 0, 0);
        }
#pragma unroll
      for (int cc = 0; cc < 2; ++cc)
#pragma unroll
        for (int r = 0; r < 4; ++r) {
          int row = rowbase + rgrp + r;
          if (row < n)
            Pt[(size_t)row * D + (cp * 2 + cc) * 16 + col16] =
                bfbits(aa[cc][r] + ac[cc][r]);
        }
    }
  }
}

// ---------------------------------------------------------------------------
// K3: typed-CSR build by (src, etype)
// ---------------------------------------------------------------------------
__global__ void zero_kernel(int* __restrict__ p, int n) {
  int i = blockIdx.x * 256 + threadIdx.x;
  if (i < n) p[i] = 0;
}

// range-blocked + XCD-pinned histogram with inline etype decode
__global__ __launch_bounds__(256) void hist5_kernel(
    const int* __restrict__ edges, const unsigned char* __restrict__ masks,
    const int* __restrict__ flag, unsigned char* __restrict__ etype8,
    int* __restrict__ cnt5, int E, int n) {
  int bx = blockIdx.x;
  int range = bx & 7;
  int e = (bx >> 3) * 256 + threadIdx.x;
  if (e >= E) return;
  int per = (n + 7) >> 3;
  int lo = range * per;
  int hi = min(lo + per, n);
  int src = edges[e];
  if (src < lo || src >= hi) return;
  int t = decode_etype(masks, E, e, *flag);
  etype8[e] = (unsigned char)t;
  atomicAdd(&cnt5[src * 8 + t], 1);
}

__global__ __launch_bounds__(256) void scanA5_kernel(const int* __restrict__ cnt5,
                                                     int* __restrict__ loc,
                                                     int* __restrict__ bsums, int n) {
  __shared__ int ts[256];
  int tid = threadIdx.x;
  int i = blockIdx.x * 256 + tid;
  int v = 0;
  if (i < n) {
    int4 c0 = *(const int4*)(cnt5 + (size_t)i * 8);
    v = c0.x + c0.y + c0.z + c0.w + cnt5[(size_t)i * 8 + 4];
  }
  ts[tid] = v;
  __syncthreads();
  for (int o = 1; o < 256; o <<= 1) {
    int t = (tid >= o) ? ts[tid - o] : 0;
    __syncthreads();
    ts[tid] += t;
    __syncthreads();
  }
  if (i < n) loc[i] = ts[tid] - v;
  if (tid == 255) bsums[blockIdx.x] = ts[255];
}

__global__ __launch_bounds__(256) void scanB_kernel(int* __restrict__ bsums, int nb,
                                                    int* __restrict__ total) {
  __shared__ int ts[256];
  int tid = threadIdx.x;
  int per = (nb + 255) / 256;
  int start = tid * per;
  int end = min(start + per, nb);
  int s = 0;
  for (int i = start; i < end; ++i) s += bsums[i];
  ts[tid] = s;
  __syncthreads();
  for (int o = 1; o < 256; o <<= 1) {
    int t = (tid >= o) ? ts[tid - o] : 0;
    __syncthreads();
    ts[tid] += t;
    __syncthreads();
  }
  int run = ts[tid] - s;
  for (int i = start; i < end; ++i) {
    int v = bsums[i];
    bsums[i] = run;
    run += v;
  }
  if (tid == 255) *total = ts[255];
}

// merged scanC+build5
__global__ void build5_kernel(const int* __restrict__ loc,
                              const int* __restrict__ bsums,
                              const int* __restrict__ cnt5,
                              int* __restrict__ cursor5, int* __restrict__ tb,
                              int n) {
  int i = blockIdx.x * 256 + threadIdx.x;
  if (i >= n) return;
  int base = loc[i] + bsums[i >> 8];
#pragma unroll
  for (int t = 0; t < NTYPES; ++t) {
    int c = cnt5[(size_t)i * 8 + t];
    cursor5[(size_t)i * 8 + t] = base;
    tb[(size_t)i * 8 + t] = base;
    base += c;
  }
  tb[(size_t)i * 8 + 5] = base;
}

// fill: range-blocked + XCD-pinned scatter
__global__ __launch_bounds__(256) void fill_kernel(
    const int* __restrict__ edges, const unsigned char* __restrict__ etype8,
    int* __restrict__ cursor5, int* __restrict__ elist, int E, int n) {
  int bx = blockIdx.x;
  int range = bx & 7;
  int e = (bx >> 3) * 256 + threadIdx.x;
  if (e >= E) return;
  int per = (n + 7) >> 3;
  int lo = range * per;
  int hi = min(lo + per, n);
  int src = edges[e];
  if (src < lo || src >= hi) return;
  int t = etype8[e];
  int dst = edges[E + e];
  int pos = atomicAdd(&cursor5[src * 8 + t], 1);
  elist[pos] = t * n + dst;
}

// ---------------------------------------------------------------------------
// K4: per-node attention over type-sorted runs. 16 lanes/node, 4 nodes/wave.
// 2-wide edge pipeline (4 gather rows in flight) + defer-max softmax.
// (4-wide was tried and regressed: VALU-bound + occupancy drop. FROZEN.)
// ---------------------------------------------------------------------------
__global__ __launch_bounds__(256, 4) void attn_kernel(
    const float* __restrict__ x, const ushort_t* __restrict__ P,
    const int* __restrict__ tb, const int* __restrict__ elist,
    float* __restrict__ out, int n) {
  int node = (blockIdx.x * 256 + threadIdx.x) >> 4;
  int gl = threadIdx.x & 15;
  if (node >= n) return;

  int4 t03 = *(const int4*)(tb + (size_t)node * 8);
  int2 t45 = *(const int2*)(tb + (size_t)node * 8 + 4);
  int bnd0 = t03.x, bnd1 = t03.y, bnd2 = t03.z, bnd3 = t03.w;
  int bnd4 = t45.x, bnd5 = t45.y;

  float m = -1e30f, den = 0.f;
  float a[8];
#pragma unroll
  for (int i = 0; i < 8; ++i) a[i] = 0.f;

#pragma unroll
  for (int t = 0; t < NTYPES; ++t) {
    int jb = (t == 0) ? bnd0 : (t == 1) ? bnd1 : (t == 2) ? bnd2
             : (t == 3) ? bnd3 : bnd4;
    int je = (t == 0) ? bnd1 : (t == 1) ? bnd2 : (t == 2) ? bnd3
             : (t == 3) ? bnd4 : bnd5;
    if (jb >= je) continue;
    bf16x8 qb = *(const bf16x8*)(P + (size_t)(t * n + node) * D + gl * 8);
    float qf[8];
#pragma unroll
    for (int d = 0; d < 8; ++d) qf[d] = (float)qb[d];

    int jlast = je - 1;
    bf16x8 kv0 = *(const bf16x8*)(P + (size_t)elist[jb] * D + gl * 8);
    int j1 = (jb + 1 < je) ? jb + 1 : jlast;
    bf16x8 kv1 = *(const bf16x8*)(P + (size_t)elist[j1] * D + gl * 8);

    for (int j = jb; j < je; j += 2) {
      int jn0 = (j + 2 < je) ? j + 2 : jlast;
      int jn1 = (j + 3 < je) ? j + 3 : jlast;
      bf16x8 nv0 = *(const bf16x8*)(P + (size_t)elist[jn0] * D + gl * 8);
      bf16x8 nv1 = *(const bf16x8*)(P + (size_t)elist[jn1] * D + gl * 8);
      float kf0[8], kf1[8], p0 = 0.f, p1 = 0.f;
#pragma unroll
      for (int d = 0; d < 8; ++d) {
        kf0[d] = (float)kv0[d];
        kf1[d] = (float)kv1[d];
        p0 += qf[d] * kf0[d];
        p1 += qf[d] * kf1[d];
      }
      p0 += __shfl_xor(p0, 1);
      p1 += __shfl_xor(p1, 1);
      p1 = (j + 1 < je) ? p1 : -1e30f;  // tail mask: exact 0 contribution
      float pmax = fmaxf(p0, p1);
      if (pmax > m + 8.f) {
        float sc = __expf(m - pmax);
        den *= sc;
#pragma unroll
        for (int d = 0; d < 8; ++d) a[d] *= sc;
        m = pmax;
      }
      float w0 = __expf(p0 - m);
      float w1 = __expf(p1 - m);
      den += w0 + w1;
#pragma unroll
      for (int d = 0; d < 8; ++d) a[d] += w0 * kf0[d] + w1 * kf1[d];
      kv0 = nv0;
      kv1 = nv1;
    }
  }

  float inv = (bnd5 > bnd0) ? 1.f / den : 0.f;
  const float* xr = x + (size_t)node * D + gl * 8;
  float* orow = out + (size_t)node * D + gl * 8;
  float4 xa = *(const float4*)xr;
  float4 xb = *(const float4*)(xr + 4);
  float4 oa, ob;
  oa.x = xa.x + a[0] * inv; oa.y = xa.y + a[1] * inv;
  oa.z = xa.z + a[2] * inv; oa.w = xa.w + a[3] * inv;
  ob.x = xb.x + a[4] * inv; ob.y = xb.y + a[5] * inv;
  ob.z = xb.z + a[6] * inv; ob.w = xb.w + a[7] * inv;
  *(float4*)orow = oa;
  *(float4*)(orow + 4) = ob;
}

// ---------------------------------------------------------------------------
// K5: fused LN2 + FFN + residual via MFMA, in-place on out (holds x2).
// 32 rows/block, barrier-free k-split (wave = (r2,ph)), single-term
// activations. Proven body (52.6 µs). FROZEN.
// ---------------------------------------------------------------------------
__global__ __launch_bounds__(256, 4) void ffn_mfma_kernel(
    const ushort_t* __restrict__ w1h, const ushort_t* __restrict__ w2h,
    const float* __restrict__ b1, const float* __restrict__ b2,
    const float* __restrict__ g, const float* __restrict__ bln,
    float* __restrict__ out, int n) {
  __shared__ char smem[16640 + 4 * 2304];
  ushort_t* z2h = (ushort_t*)smem;
  float* red = (float*)smem;
  int tid = threadIdx.x, w = tid >> 6, l = tid & 63;
  int n0 = blockIdx.x * 32;
  int r2 = w & 1, ph = w >> 1;
  float* hbw = (float*)(smem + 16640) + w * 576;

  for (int i = w; i < 32; i += 4) {
    int r = n0 + i;
    float v0 = 0.f, v1 = 0.f;
    if (r < n) {
      v0 = out[(size_t)r * D + l];
      v1 = out[(size_t)r * D + 64 + l];
    }
    float s = v0 + v1, ss = v0 * v0 + v1 * v1;
    for (int o = 32; o; o >>= 1) { s += __shfl_xor(s, o); ss += __shfl_xor(ss, o); }
    float mu = s * (1.f / D);
    float var = ss * (1.f / D) - mu * mu;
    float rs = rsqrtf(var + LN_EPS);
    float z0 = (v0 - mu) * rs * g[l] + bln[l];
    float z1 = (v1 - mu) * rs * g[l + 64] + bln[l + 64];
    int sw = (i & 7) << 3;
    int e0 = (i * D + l) ^ sw;
    int e1 = (i * D + l + 64) ^ sw;
    __bf16 h0 = (__bf16)z0, h1 = (__bf16)z1;
    z2h[e0] = __builtin_bit_cast(ushort_t, h0);
    z2h[e1] = __builtin_bit_cast(ushort_t, h1);
  }
  __syncthreads();

  int lrow = r2 * 16 + (l & 15);
  int koff = (l >> 4) * 8;
  bf16x8 ah[4];
#pragma unroll
  for (int kk = 0; kk < 4; ++kk) {
    int e = (lrow * D + kk * 32 + koff) ^ ((lrow & 7) << 3);
    ah[kk] = *(const bf16x8*)(z2h + e);
  }
  __syncthreads();

  int col16 = l & 15, rgrp = (l >> 4) * 4;
  f32x4 acc2[8];
#pragma unroll
  for (int c = 0; c < 8; ++c) acc2[c] = (f32x4){0.f, 0.f, 0.f, 0.f};

  for (int i = 0; i < 8; ++i) {
    int kk2 = 2 * i + ph;
    bf16x8 B1h[2][4];
#pragma unroll
    for (int cc = 0; cc < 2; ++cc)
#pragma unroll
      for (int kk = 0; kk < 4; ++kk) {
        size_t o = ((size_t)((kk2 * 2 + cc) * 4 + kk) * 64 + l) * 8;
        B1h[cc][kk] = *(const bf16x8*)(w1h + o);
      }
    f32x4 ha[2];
#pragma unroll
    for (int cc = 0; cc < 2; ++cc) {
      float bias = b1[(kk2 * 2 + cc) * 16 + col16];
      ha[cc] = (f32x4){bias, bias, bias, bias};
    }
#pragma unroll
    for (int kk = 0; kk < 4; ++kk)
#pragma unroll
      for (int cc = 0; cc < 2; ++cc)
        ha[cc] = __builtin_amdgcn_mfma_f32_16x16x32_bf16(ah[kk], B1h[cc][kk], ha[cc], 0, 0, 0);
#pragma unroll
    for (int cc = 0; cc < 2; ++cc)
#pragma unroll
      for (int r = 0; r < 4; ++r)
        hbw[(rgrp + r) * 36 + cc * 16 + col16] = fmaxf(ha[cc][r], 0.f);
    float av[8];
    *(float4*)&av[0] = *(const float4*)&hbw[(l & 15) * 36 + koff];
    *(float4*)&av[4] = *(const float4*)&hbw[(l & 15) * 36 + koff + 4];
    bf16x8 a2h;
#pragma unroll
    for (int j = 0; j < 8; ++j) a2h[j] = (__bf16)av[j];
#pragma unroll
    for (int half = 0; half < 2; ++half) {
      bf16x8 B2h[4];
#pragma unroll
      for (int c2 = 0; c2 < 4; ++c2) {
        int ct = half * 4 + c2;
        size_t o = ((size_t)(ct * 16 + kk2) * 64 + l) * 8;
        B2h[c2] = *(const bf16x8*)(w2h + o);
      }
#pragma unroll
      for (int c2 = 0; c2 < 4; ++c2) {
        int ct = half * 4 + c2;
        acc2[ct] = __builtin_amdgcn_mfma_f32_16x16x32_bf16(a2h, B2h[c2], acc2[ct], 0, 0, 0);
      }
    }
  }

  if (ph == 0) {
#pragma unroll
    for (int ct = 0; ct < 8; ++ct)
#pragma unroll
      for (int r = 0; r < 4; ++r)
        red[(r2 * 16 + rgrp + r) * 130 + ct * 16 + col16] = acc2[ct][r];
  }
  __syncthreads();
  if (ph == 1) {
#pragma unroll
    for (int ct = 0; ct < 8; ++ct) {
      int col = ct * 16 + col16;
      float bias2 = b2[col];
#pragma unroll
      for (int r = 0; r < 4; ++r) {
        int row = n0 + r2 * 16 + rgrp + r;
        if (row < n) {
          float part = red[(r2 * 16 + rgrp + r) * 130 + col];
          size_t o = (size_t)row * D + col;
          out[o] = out[o] + acc2[ct][r] + part + bias2;
        }
      }
    }
  }
}

// ---------------------------------------------------------------------------
extern "C" void kernel_launch(void* const* d_in, const int* in_sizes, int n_in,
                              void* d_out, int out_size, void* d_ws, size_t ws_size,
                              hipStream_t stream) {
  const float* x      = (const float*)d_in[0];
  const int* edges    = (const int*)d_in[1];
  const unsigned char* masks = (const unsigned char*)d_in[2];
  const float* Wk     = (const float*)d_in[3];
  const float* bk     = (const float*)d_in[4];
  const float* ln1_g  = (const float*)d_in[5];
  const float* ln1_b  = (const float*)d_in[6];
  const float* ln2_g  = (const float*)d_in[7];
  const float* ln2_b  = (const float*)d_in[8];
  const float* W1     = (const float*)d_in[9];
  const float* b1     = (const float*)d_in[10];
  const float* W2     = (const float*)d_in[11];
  const float* b2     = (const float*)d_in[12];
  float* out = (float*)d_out;

  const int n = in_sizes[0] / D;
  const int E = in_sizes[1] / 2;
  const int nbn = (n + 255) / 256;

  // workspace layout (~74 MB)
  char* ws = (char*)d_ws;
  size_t off = 0;
  ushort_t* P = (ushort_t*)(ws + off);  off += (size_t)NTYPES * n * D * sizeof(ushort_t);
  int* cnt5   = (int*)(ws + off);       off += (size_t)n * 8 * sizeof(int);
  int* cursor5= (int*)(ws + off);       off += (size_t)n * 8 * sizeof(int);
  int* tb     = (int*)(ws + off);       off += (size_t)n * 8 * sizeof(int);
  int* loc    = (int*)(ws + off);       off += (size_t)n * sizeof(int);
  int* bsums  = (int*)(ws + off);       off += (size_t)nbn * sizeof(int);
  int* total  = (int*)(ws + off);       off += 64;
  int* elist  = (int*)(ws + off);       off += (size_t)E * sizeof(int);
  unsigned char* etype8 = (unsigned char*)(ws + off); off += (size_t)E + 64;
  int* flag   = (int*)(ws + off);       off += 64;
  ushort_t* wkh = (ushort_t*)(ws + off); off += (size_t)NTYPES * D * D * sizeof(ushort_t);
  ushort_t* w1h = (ushort_t*)(ws + off); off += (size_t)D * FFDIM * sizeof(ushort_t);
  ushort_t* w2h = (ushort_t*)(ws + off); off += (size_t)FFDIM * D * sizeof(ushort_t);
  (void)ws_size; (void)n_in; (void)out_size;

  // K0: mask dtype detection
  detect_kernel<<<1, 64, 0, stream>>>(masks, E, flag);

  // K1b: weight fragment conversion (hi only)
  {
    dim3 gwk((8 * 4 * 64 + 255) / 256, NTYPES);
    conv_frag_kernel<<<gwk, 256, 0, stream>>>(Wk, wkh, D, D,
                                              (size_t)D * D, (size_t)D * D);
    dim3 gw1(((FFDIM / 16) * 4 * 64 + 255) / 256, 1);
    conv_frag_kernel<<<gw1, 256, 0, stream>>>(W1, w1h, D, FFDIM, 0, 0);
    dim3 gw2((8 * (FFDIM / 32) * 64 + 255) / 256, 1);
    conv_frag_kernel<<<gw2, 256, 0, stream>>>(W2, w2h, FFDIM, D, 0, 0);
  }

  // K2: fused LN1 + projections
  projln_kernel<<<(n + 63) / 64, 256, 0, stream>>>(x, ln1_g, ln1_b, wkh, bk, P, n);

  // K3: typed-CSR build (etype decode fused into hist5)
  zero_kernel<<<(n * 8 + 255) / 256, 256, 0, stream>>>(cnt5, n * 8);
  hist5_kernel<<<((E + 255) / 256) * 8, 256, 0, stream>>>(edges, masks, flag,
                                                          etype8, cnt5, E, n);
  scanA5_kernel<<<nbn, 256, 0, stream>>>(cnt5, loc, bsums, n);
  scanB_kernel<<<1, 256, 0, stream>>>(bsums, nbn, total);
  build5_kernel<<<(n + 255) / 256, 256, 0, stream>>>(loc, bsums, cnt5, cursor5, tb, n);
  fill_kernel<<<((E + 255) / 256) * 8, 256, 0, stream>>>(edges, etype8, cursor5,
                                                         elist, E, n);

  // K4: attention -> out = x + attn (2-wide edge pipeline)
  attn_kernel<<<(n + 15) / 16, 256, 0, stream>>>(x, P, tb, elist, out, n);

  // K5: LN2 + FFN + residual (32 rows/block, barrier-free k-split)
  ffn_mfma_kernel<<<(n + 31) / 32, 256, 0, stream>>>(w1h, w2h,
                                                     b1, b2, ln2_g, ln2_b, out, n);
}